// Round 2
// baseline (485.061 us; speedup 1.0000x reference)
//
#include <hip/hip_runtime.h>
#include <stdint.h>

// Problem constants
#define T_DIM 2048
#define B_DIM 4
#define D_DIM 1024
#define H_NUM 16
#define HD 64
#define MROWS (T_DIM * B_DIM)     // 8192 flattened (t*B+b) rows
#define QKV_N (3 * D_DIM)         // 3072
#define ATT_SCALE 0.125f          // 1/sqrt(64)

typedef unsigned short u16;
typedef __bf16 bf16x8 __attribute__((ext_vector_type(8)));
typedef float f32x4 __attribute__((ext_vector_type(4)));
typedef u16 u16x4 __attribute__((ext_vector_type(4)));
typedef u16 u16x8 __attribute__((ext_vector_type(8)));

__device__ __forceinline__ u16 f2bf(float f) {
  union { float f; unsigned u; } v; v.f = f;
  unsigned r = v.u + 0x7fffu + ((v.u >> 16) & 1u);
  return (u16)(r >> 16);
}

__device__ __forceinline__ void async_copy16(void* lds, const void* g) {
  __builtin_amdgcn_global_load_lds((__attribute__((address_space(1))) void*)(g),
                                   (__attribute__((address_space(3))) void*)(lds),
                                   16, 0, 0);
}

// ---------------- fp32 -> bf16 cast (memory-bound) ----------------
__global__ __launch_bounds__(256) void cast_f32_bf16(
    const float* __restrict__ src, u16* __restrict__ dst, int n4) {
  int i = blockIdx.x * 256 + threadIdx.x;
  if (i >= n4) return;
  float4 v = reinterpret_cast<const float4*>(src)[i];
  u16x4 o = {f2bf(v.x), f2bf(v.y), f2bf(v.z), f2bf(v.w)};
  reinterpret_cast<u16x4*>(dst)[i] = o;
}

// ---------------- bf16 GEMM: C[M][N] = A[M][K] * B[N][K]^T ----------------
// m97 structure (unchanged this round).
template <int OUT_F32_BIAS>
__global__ __launch_bounds__(256) void gemm_bt(
    const u16* __restrict__ A, const u16* __restrict__ Bm,
    u16* __restrict__ Cb, float* __restrict__ Cf, const float* __restrict__ bias,
    int M, int N, int K) {
  __shared__ __attribute__((aligned(16))) u16 As[128 * 64];
  __shared__ __attribute__((aligned(16))) u16 Bs[128 * 64];

  const int tid = threadIdx.x;
  const int lane = tid & 63, wid = tid >> 6;
  const int l15 = lane & 15, lg = lane >> 4;
  const int wr = wid >> 1, wc = wid & 1;
  const int m0 = blockIdx.y * 128, n0 = blockIdx.x * 128;

  f32x4 acc[4][4];
#pragma unroll
  for (int i = 0; i < 4; i++)
#pragma unroll
    for (int j = 0; j < 4; j++) acc[i][j] = (f32x4){0.f, 0.f, 0.f, 0.f};

  const int srow = tid >> 3;
  const int scol = (tid & 7) * 8;
  const u16* gA = A + (size_t)(m0 + srow) * K + scol;
  const u16* gB = Bm + (size_t)(n0 + srow) * K + scol;
  u16* lA = As + tid * 8;
  u16* lB = Bs + tid * 8;

  const int KT = K >> 6;
  for (int kt = 0; kt < KT; ++kt) {
    const int kofs = kt * 64;
#pragma unroll
    for (int p = 0; p < 4; ++p) {
      async_copy16(lA + p * 256 * 8, gA + (size_t)(p * 32) * K + kofs);
      async_copy16(lB + p * 256 * 8, gB + (size_t)(p * 32) * K + kofs);
    }
    __syncthreads();
#pragma unroll
    for (int kk = 0; kk < 2; ++kk) {
      bf16x8 af[4], bfr[4];
#pragma unroll
      for (int mt = 0; mt < 4; ++mt)
        af[mt] = *reinterpret_cast<const bf16x8*>(
            &As[(wr * 64 + mt * 16 + l15) * 64 + kk * 32 + lg * 8]);
#pragma unroll
      for (int nt = 0; nt < 4; ++nt)
        bfr[nt] = *reinterpret_cast<const bf16x8*>(
            &Bs[(wc * 64 + nt * 16 + l15) * 64 + kk * 32 + lg * 8]);
#pragma unroll
      for (int mt = 0; mt < 4; ++mt)
#pragma unroll
        for (int nt = 0; nt < 4; ++nt)
          acc[mt][nt] = __builtin_amdgcn_mfma_f32_16x16x32_bf16(
              af[mt], bfr[nt], acc[mt][nt], 0, 0, 0);
    }
    __syncthreads();
  }

#pragma unroll
  for (int mt = 0; mt < 4; ++mt) {
#pragma unroll
    for (int r = 0; r < 4; ++r) {
      const int row = m0 + wr * 64 + mt * 16 + lg * 4 + r;
#pragma unroll
      for (int nt = 0; nt < 4; ++nt) {
        const int col = n0 + wc * 64 + nt * 16 + l15;
        float v = acc[mt][nt][r];
        if (OUT_F32_BIAS) {
          Cf[(size_t)row * N + col] = v + bias[col];
        } else {
          Cb[(size_t)row * N + col] = f2bf(v);
        }
      }
    }
  }
}

// ---------------- causal flash attention, paired q-tiles ----------------
// Grid: (16, B*H). Block px handles q-tiles qtA=px and qtB=31-px -> uniform
// 33 kv-tile iterations per block; K/V staging + fragment loads shared by
// both q-tiles. K and P LDS are XOR-swizzled (chunk ^= row&7) to kill the
// 16-way bank conflict of 128B-stride rows.
__device__ __forceinline__ void softmax_tile(
    f32x4 (&s)[4], float (&mrow)[4], float (&lrow)[4], f32x4 (&acc_o)[4],
    bool diag, int rowbase, int kv0, int l15, int lg, u16* __restrict__ Pw) {
#pragma unroll
  for (int jt = 0; jt < 4; ++jt)
#pragma unroll
    for (int r = 0; r < 4; ++r) {
      float v = s[jt][r] * ATT_SCALE;
      if (diag) {
        const int col = kv0 + jt * 16 + l15;
        const int row = rowbase + lg * 4 + r;
        if (col > row) v = -1e30f;
      }
      s[jt][r] = v;
    }
#pragma unroll
  for (int r = 0; r < 4; ++r) {
    float mx = fmaxf(fmaxf(s[0][r], s[1][r]), fmaxf(s[2][r], s[3][r]));
#pragma unroll
    for (int off = 1; off < 16; off <<= 1) mx = fmaxf(mx, __shfl_xor(mx, off, 64));
    const float mnew = fmaxf(mrow[r], mx);
    const float corr = __expf(mrow[r] - mnew);
    mrow[r] = mnew;
    float rs = 0.f;
#pragma unroll
    for (int jt = 0; jt < 4; ++jt) {
      float p = __expf(s[jt][r] - mnew);
      s[jt][r] = p;
      rs += p;
    }
#pragma unroll
    for (int off = 1; off < 16; off <<= 1) rs += __shfl_xor(rs, off, 64);
    lrow[r] = lrow[r] * corr + rs;
#pragma unroll
    for (int dj = 0; dj < 4; ++dj) acc_o[dj][r] *= corr;
  }
  // P -> LDS, swizzled at 8-u16 granularity
#pragma unroll
  for (int jt = 0; jt < 4; ++jt)
#pragma unroll
    for (int r = 0; r < 4; ++r) {
      const int row = lg * 4 + r;
      const int col = jt * 16 + l15;
      Pw[row * 64 + (col ^ ((row & 7) * 8))] = f2bf(s[jt][r]);
    }
}

__global__ __launch_bounds__(256, 4) void attn_kernel(
    const u16* __restrict__ qkv, u16* __restrict__ aout) {
  __shared__ __attribute__((aligned(16))) u16 Ks[64 * 64];        // swizzled
  __shared__ __attribute__((aligned(16))) u16 Vf[2 * 4 * 64 * 8]; // V B-frags
  __shared__ __attribute__((aligned(16))) u16 Ps[4][2][16 * 64];  // swizzled

  const int tid = threadIdx.x;
  const int lane = tid & 63, w = tid >> 6;
  const int l15 = lane & 15, lg = lane >> 4;
  const int px = blockIdx.x;
  const int bh = blockIdx.y;
  const int b = bh >> 4, h = bh & 15;
  const int qtA = px, qtB = 31 - px;      // qtA < qtB always
  const int qAbase = qtA * 64 + w * 16;
  const int qBbase = qtB * 64 + w * 16;

  // Q fragments (held in registers for the whole kernel), both tiles
  bf16x8 aqA[2], aqB[2];
  {
    const u16* qpA = qkv + ((size_t)(qAbase + l15) * B_DIM + b) * QKV_N + h * HD + lg * 8;
    const u16* qpB = qkv + ((size_t)(qBbase + l15) * B_DIM + b) * QKV_N + h * HD + lg * 8;
    aqA[0] = *reinterpret_cast<const bf16x8*>(qpA);
    aqA[1] = *reinterpret_cast<const bf16x8*>(qpA + 32);
    aqB[0] = *reinterpret_cast<const bf16x8*>(qpB);
    aqB[1] = *reinterpret_cast<const bf16x8*>(qpB + 32);
  }

  f32x4 accA[4], accB[4];
#pragma unroll
  for (int i = 0; i < 4; i++) {
    accA[i] = (f32x4){0.f, 0.f, 0.f, 0.f};
    accB[i] = (f32x4){0.f, 0.f, 0.f, 0.f};
  }
  float mA[4] = {-1e30f, -1e30f, -1e30f, -1e30f}, lA_[4] = {0.f, 0.f, 0.f, 0.f};
  float mB[4] = {-1e30f, -1e30f, -1e30f, -1e30f}, lB_[4] = {0.f, 0.f, 0.f, 0.f};

  const int srow = tid >> 3;            // 0..31
  const int scol = (tid & 7) * 8;
  const int c16sw = (tid & 7) ^ (srow & 7);  // pre-swizzled K source chunk
  u16* lK = Ks + tid * 8;

  for (int kt = 0; kt <= qtB; ++kt) {
    const int kv0 = kt * 64;
    const bool doLow = (kt <= qtA);
    // stage K tile swizzled: linear LDS dest, inverse-swizzled global source
#pragma unroll
    for (int p = 0; p < 2; ++p) {
      const u16* gK = qkv + ((size_t)(kv0 + p * 32 + srow) * B_DIM + b) * QKV_N +
                      D_DIM + h * HD + c16sw * 8;
      async_copy16(lK + p * 256 * 8, gK);
    }
    // V: global -> regs -> scatter into MFMA B-fragment layout
    u16x8 vv[2];
#pragma unroll
    for (int p = 0; p < 2; ++p) {
      const u16* gV = qkv + ((size_t)(kv0 + p * 32 + srow) * B_DIM + b) * QKV_N +
                      2 * D_DIM + h * HD + scol;
      vv[p] = *reinterpret_cast<const u16x8*>(gV);
    }
#pragma unroll
    for (int p = 0; p < 2; ++p) {
      const int jj = srow & 7;
      const int lgrp = srow >> 3;
#pragma unroll
      for (int j = 0; j < 8; ++j) {
        const int d = scol + j;
        Vf[(((p * 4) + (d >> 4)) * 64 + lgrp * 16 + (d & 15)) * 8 + jj] = vv[p][j];
      }
    }
    __syncthreads();

    // S = Q K^T for both q-tiles, sharing the K fragments
    f32x4 sA[4], sB[4];
#pragma unroll
    for (int jt = 0; jt < 4; jt++) {
      sA[jt] = (f32x4){0.f, 0.f, 0.f, 0.f};
      sB[jt] = (f32x4){0.f, 0.f, 0.f, 0.f};
    }
    __builtin_amdgcn_s_setprio(1);
#pragma unroll
    for (int kk = 0; kk < 2; ++kk) {
#pragma unroll
      for (int jt = 0; jt < 4; ++jt) {
        const int row = jt * 16 + l15;
        bf16x8 bk = *reinterpret_cast<const bf16x8*>(
            &Ks[row * 64 + ((kk * 32 + lg * 8) ^ ((row & 7) * 8))]);
        if (doLow)
          sA[jt] = __builtin_amdgcn_mfma_f32_16x16x32_bf16(aqA[kk], bk, sA[jt], 0, 0, 0);
        sB[jt] = __builtin_amdgcn_mfma_f32_16x16x32_bf16(aqB[kk], bk, sB[jt], 0, 0, 0);
      }
    }
    __builtin_amdgcn_s_setprio(0);

    if (doLow)
      softmax_tile(sA, mA, lA_, accA, kt == qtA, qAbase, kv0, l15, lg, &Ps[w][0][0]);
    softmax_tile(sB, mB, lB_, accB, kt == qtB, qBbase, kv0, l15, lg, &Ps[w][1][0]);

    // O += P V for both q-tiles, sharing the V fragments
    __builtin_amdgcn_s_setprio(1);
#pragma unroll
    for (int ks = 0; ks < 2; ++ks) {
      const int poff = l15 * 64 + ((ks * 32 + lg * 8) ^ ((l15 & 7) * 8));
      bf16x8 apA, apB;
      if (doLow) apA = *reinterpret_cast<const bf16x8*>(&Ps[w][0][poff]);
      apB = *reinterpret_cast<const bf16x8*>(&Ps[w][1][poff]);
#pragma unroll
      for (int dj = 0; dj < 4; ++dj) {
        bf16x8 bv = *reinterpret_cast<const bf16x8*>(&Vf[((ks * 4 + dj) * 64 + lane) * 8]);
        if (doLow)
          accA[dj] = __builtin_amdgcn_mfma_f32_16x16x32_bf16(apA, bv, accA[dj], 0, 0, 0);
        accB[dj] = __builtin_amdgcn_mfma_f32_16x16x32_bf16(apB, bv, accB[dj], 0, 0, 0);
      }
    }
    __builtin_amdgcn_s_setprio(0);
    __syncthreads();
  }

  // epilogue: O /= lsum, write bf16 for both q-tiles
#pragma unroll
  for (int r = 0; r < 4; ++r) {
    const float invA = 1.0f / lA_[r];
    const float invB = 1.0f / lB_[r];
    u16* opA = aout + ((size_t)(qAbase + lg * 4 + r) * B_DIM + b) * D_DIM + h * HD;
    u16* opB = aout + ((size_t)(qBbase + lg * 4 + r) * B_DIM + b) * D_DIM + h * HD;
#pragma unroll
    for (int dj = 0; dj < 4; ++dj) {
      opA[dj * 16 + l15] = f2bf(accA[dj][r] * invA);
      opB[dj * 16 + l15] = f2bf(accB[dj][r] * invB);
    }
  }
}

// ---------------- launch ----------------
extern "C" void kernel_launch(void* const* d_in, const int* in_sizes, int n_in,
                              void* d_out, int out_size, void* d_ws, size_t ws_size,
                              hipStream_t stream) {
  (void)in_sizes; (void)n_in; (void)out_size; (void)ws_size;
  const float* x = (const float*)d_in[0];
  const float* Wqkv = (const float*)d_in[1];
  const float* Wout = (const float*)d_in[2];
  const float* bout = (const float*)d_in[3];
  float* out = (float*)d_out;

  u16* xb = (u16*)d_ws;                               // [8192][1024]
  u16* wqkvb = xb + (size_t)MROWS * D_DIM;            // [3072][1024]
  u16* woutb = wqkvb + (size_t)QKV_N * D_DIM;         // [1024][1024]
  u16* qkv = woutb + (size_t)D_DIM * D_DIM;           // [8192][3072]
  u16* aout = qkv + (size_t)MROWS * QKV_N;            // [8192][1024]

  {
    int n4 = MROWS * D_DIM / 4;
    cast_f32_bf16<<<(n4 + 255) / 256, 256, 0, stream>>>(x, xb, n4);
  }
  {
    int n4 = QKV_N * D_DIM / 4;
    cast_f32_bf16<<<(n4 + 255) / 256, 256, 0, stream>>>(Wqkv, wqkvb, n4);
  }
  {
    int n4 = D_DIM * D_DIM / 4;
    cast_f32_bf16<<<(n4 + 255) / 256, 256, 0, stream>>>(Wout, woutb, n4);
  }

  gemm_bt<0><<<dim3(QKV_N / 128, MROWS / 128), 256, 0, stream>>>(
      xb, wqkvb, qkv, nullptr, nullptr, MROWS, QKV_N, D_DIM);

  attn_kernel<<<dim3(16, B_DIM * H_NUM), 256, 0, stream>>>(qkv, aout);

  gemm_bt<1><<<dim3(D_DIM / 128, MROWS / 128), 256, 0, stream>>>(
      aout, woutb, nullptr, out, bout, MROWS, D_DIM, D_DIM);
}

// Round 3
// 308.005 us; speedup vs baseline: 1.5748x; 1.5748x over previous
//
#include <hip/hip_runtime.h>
#include <stdint.h>

// Problem constants
#define T_DIM 2048
#define B_DIM 4
#define D_DIM 1024
#define H_NUM 16
#define HD 64
#define MROWS (T_DIM * B_DIM)     // 8192 flattened (t*B+b) rows
#define QKV_N (3 * D_DIM)         // 3072
#define ATT_SCALE 0.125f          // 1/sqrt(64)

typedef unsigned short u16;
typedef __bf16 bf16x8 __attribute__((ext_vector_type(8)));
typedef float f32x4 __attribute__((ext_vector_type(4)));
typedef u16 u16x4 __attribute__((ext_vector_type(4)));
typedef u16 u16x8 __attribute__((ext_vector_type(8)));

__device__ __forceinline__ u16 f2bf(float f) {
  union { float f; unsigned u; } v; v.f = f;
  unsigned r = v.u + 0x7fffu + ((v.u >> 16) & 1u);
  return (u16)(r >> 16);
}

__device__ __forceinline__ void async_copy16(void* lds, const void* g) {
  __builtin_amdgcn_global_load_lds((__attribute__((address_space(1))) void*)(g),
                                   (__attribute__((address_space(3))) void*)(lds),
                                   16, 0, 0);
}

// ---------------- fp32 -> bf16 cast (memory-bound) ----------------
__global__ __launch_bounds__(256) void cast_f32_bf16(
    const float* __restrict__ src, u16* __restrict__ dst, int n4) {
  int i = blockIdx.x * 256 + threadIdx.x;
  if (i >= n4) return;
  float4 v = reinterpret_cast<const float4*>(src)[i];
  u16x4 o = {f2bf(v.x), f2bf(v.y), f2bf(v.z), f2bf(v.w)};
  reinterpret_cast<u16x4*>(dst)[i] = o;
}

// ---------------- bf16 GEMM: C[M][N] = A[M][K] * B[N][K]^T ----------------
// m97 structure (unchanged this round).
template <int OUT_F32_BIAS>
__global__ __launch_bounds__(256) void gemm_bt(
    const u16* __restrict__ A, const u16* __restrict__ Bm,
    u16* __restrict__ Cb, float* __restrict__ Cf, const float* __restrict__ bias,
    int M, int N, int K) {
  __shared__ __attribute__((aligned(16))) u16 As[128 * 64];
  __shared__ __attribute__((aligned(16))) u16 Bs[128 * 64];

  const int tid = threadIdx.x;
  const int lane = tid & 63, wid = tid >> 6;
  const int l15 = lane & 15, lg = lane >> 4;
  const int wr = wid >> 1, wc = wid & 1;
  const int m0 = blockIdx.y * 128, n0 = blockIdx.x * 128;

  f32x4 acc[4][4];
#pragma unroll
  for (int i = 0; i < 4; i++)
#pragma unroll
    for (int j = 0; j < 4; j++) acc[i][j] = (f32x4){0.f, 0.f, 0.f, 0.f};

  const int srow = tid >> 3;
  const int scol = (tid & 7) * 8;
  const u16* gA = A + (size_t)(m0 + srow) * K + scol;
  const u16* gB = Bm + (size_t)(n0 + srow) * K + scol;
  u16* lA = As + tid * 8;
  u16* lB = Bs + tid * 8;

  const int KT = K >> 6;
  for (int kt = 0; kt < KT; ++kt) {
    const int kofs = kt * 64;
#pragma unroll
    for (int p = 0; p < 4; ++p) {
      async_copy16(lA + p * 256 * 8, gA + (size_t)(p * 32) * K + kofs);
      async_copy16(lB + p * 256 * 8, gB + (size_t)(p * 32) * K + kofs);
    }
    __syncthreads();
#pragma unroll
    for (int kk = 0; kk < 2; ++kk) {
      bf16x8 af[4], bfr[4];
#pragma unroll
      for (int mt = 0; mt < 4; ++mt)
        af[mt] = *reinterpret_cast<const bf16x8*>(
            &As[(wr * 64 + mt * 16 + l15) * 64 + kk * 32 + lg * 8]);
#pragma unroll
      for (int nt = 0; nt < 4; ++nt)
        bfr[nt] = *reinterpret_cast<const bf16x8*>(
            &Bs[(wc * 64 + nt * 16 + l15) * 64 + kk * 32 + lg * 8]);
#pragma unroll
      for (int mt = 0; mt < 4; ++mt)
#pragma unroll
        for (int nt = 0; nt < 4; ++nt)
          acc[mt][nt] = __builtin_amdgcn_mfma_f32_16x16x32_bf16(
              af[mt], bfr[nt], acc[mt][nt], 0, 0, 0);
    }
    __syncthreads();
  }

#pragma unroll
  for (int mt = 0; mt < 4; ++mt) {
#pragma unroll
    for (int r = 0; r < 4; ++r) {
      const int row = m0 + wr * 64 + mt * 16 + lg * 4 + r;
#pragma unroll
      for (int nt = 0; nt < 4; ++nt) {
        const int col = n0 + wc * 64 + nt * 16 + l15;
        float v = acc[mt][nt][r];
        if (OUT_F32_BIAS) {
          Cf[(size_t)row * N + col] = v + bias[col];
        } else {
          Cb[(size_t)row * N + col] = f2bf(v);
        }
      }
    }
  }
}

// ---------------- causal flash attention, paired q-tiles ----------------
// Grid: (16, B*H). Block px handles q-tiles qtA=px and qtB=31-px -> uniform
// 33 kv-tile iterations per block. K/V staging shared; tiles processed
// SEQUENTIALLY (A then B) to keep one live S-state -> no spills.
// K and P LDS XOR-swizzled (8-u16 chunk ^= row&7) against 128B-stride rows.

// Process one 16x64 q-tile against the staged kv tile. Everything inlined.
__device__ __forceinline__ void process_tile(
    const bf16x8 (&aq)[2], f32x4 (&acc_o)[4], float (&mrow)[4], float (&lrow)[4],
    bool diag, int rowbase, int kv0, int l15, int lg,
    const u16* __restrict__ Ks, const u16* __restrict__ Vf, u16* __restrict__ Pw) {
  f32x4 s[4];
#pragma unroll
  for (int jt = 0; jt < 4; ++jt) s[jt] = (f32x4){0.f, 0.f, 0.f, 0.f};
  __builtin_amdgcn_s_setprio(1);
#pragma unroll
  for (int kk = 0; kk < 2; ++kk) {
#pragma unroll
    for (int jt = 0; jt < 4; ++jt) {
      const int row = jt * 16 + l15;
      bf16x8 bk = *reinterpret_cast<const bf16x8*>(
          &Ks[row * 64 + ((kk * 32 + lg * 8) ^ ((row & 7) * 8))]);
      s[jt] = __builtin_amdgcn_mfma_f32_16x16x32_bf16(aq[kk], bk, s[jt], 0, 0, 0);
    }
  }
  __builtin_amdgcn_s_setprio(0);
  // scale + causal mask
#pragma unroll
  for (int jt = 0; jt < 4; ++jt)
#pragma unroll
    for (int r = 0; r < 4; ++r) {
      float v = s[jt][r] * ATT_SCALE;
      if (diag) {
        const int col = kv0 + jt * 16 + l15;
        const int row = rowbase + lg * 4 + r;
        if (col > row) v = -1e30f;
      }
      s[jt][r] = v;
    }
  // online softmax (rows spread over 16-lane groups)
#pragma unroll
  for (int r = 0; r < 4; ++r) {
    float mx = fmaxf(fmaxf(s[0][r], s[1][r]), fmaxf(s[2][r], s[3][r]));
#pragma unroll
    for (int off = 1; off < 16; off <<= 1) mx = fmaxf(mx, __shfl_xor(mx, off, 64));
    const float mnew = fmaxf(mrow[r], mx);
    const float corr = __expf(mrow[r] - mnew);
    mrow[r] = mnew;
    float rs = 0.f;
#pragma unroll
    for (int jt = 0; jt < 4; ++jt) {
      float p = __expf(s[jt][r] - mnew);
      s[jt][r] = p;
      rs += p;
    }
#pragma unroll
    for (int off = 1; off < 16; off <<= 1) rs += __shfl_xor(rs, off, 64);
    lrow[r] = lrow[r] * corr + rs;
#pragma unroll
    for (int dj = 0; dj < 4; ++dj) acc_o[dj][r] *= corr;
  }
  // P -> LDS (per-wave buffer, swizzled)
#pragma unroll
  for (int jt = 0; jt < 4; ++jt)
#pragma unroll
    for (int r = 0; r < 4; ++r) {
      const int row = lg * 4 + r;
      const int col = jt * 16 + l15;
      Pw[row * 64 + (col ^ ((row & 7) * 8))] = f2bf(s[jt][r]);
    }
  // O += P V
  __builtin_amdgcn_s_setprio(1);
#pragma unroll
  for (int ks = 0; ks < 2; ++ks) {
    bf16x8 ap = *reinterpret_cast<const bf16x8*>(
        &Pw[l15 * 64 + ((ks * 32 + lg * 8) ^ ((l15 & 7) * 8))]);
#pragma unroll
    for (int dj = 0; dj < 4; ++dj) {
      bf16x8 bv = *reinterpret_cast<const bf16x8*>(
          &Vf[((ks * 4 + dj) * 64 + (l15 | (lg << 4))) * 8]);
      acc_o[dj] = __builtin_amdgcn_mfma_f32_16x16x32_bf16(ap, bv, acc_o[dj], 0, 0, 0);
    }
  }
  __builtin_amdgcn_s_setprio(0);
}

__global__ __launch_bounds__(256, 2) void attn_kernel(
    const u16* __restrict__ qkv, u16* __restrict__ aout) {
  __shared__ __attribute__((aligned(16))) u16 Ks[64 * 64];        // swizzled
  __shared__ __attribute__((aligned(16))) u16 Vf[2 * 4 * 64 * 8]; // V B-frags
  __shared__ __attribute__((aligned(16))) u16 Ps[4][16 * 64];     // per-wave P

  const int tid = threadIdx.x;
  const int lane = tid & 63, w = tid >> 6;
  const int l15 = lane & 15, lg = lane >> 4;
  const int px = blockIdx.x;
  const int bh = blockIdx.y;
  const int b = bh >> 4, h = bh & 15;
  const int qtA = px, qtB = 31 - px;      // qtA < qtB always
  const int qAbase = qtA * 64 + w * 16;
  const int qBbase = qtB * 64 + w * 16;

  bf16x8 aqA[2], aqB[2];
  {
    const u16* qpA = qkv + ((size_t)(qAbase + l15) * B_DIM + b) * QKV_N + h * HD + lg * 8;
    const u16* qpB = qkv + ((size_t)(qBbase + l15) * B_DIM + b) * QKV_N + h * HD + lg * 8;
    aqA[0] = *reinterpret_cast<const bf16x8*>(qpA);
    aqA[1] = *reinterpret_cast<const bf16x8*>(qpA + 32);
    aqB[0] = *reinterpret_cast<const bf16x8*>(qpB);
    aqB[1] = *reinterpret_cast<const bf16x8*>(qpB + 32);
  }

  f32x4 accA[4], accB[4];
#pragma unroll
  for (int i = 0; i < 4; i++) {
    accA[i] = (f32x4){0.f, 0.f, 0.f, 0.f};
    accB[i] = (f32x4){0.f, 0.f, 0.f, 0.f};
  }
  float mA[4] = {-1e30f, -1e30f, -1e30f, -1e30f}, lA_[4] = {0.f, 0.f, 0.f, 0.f};
  float mB[4] = {-1e30f, -1e30f, -1e30f, -1e30f}, lB_[4] = {0.f, 0.f, 0.f, 0.f};

  const int srow = tid >> 3;                 // 0..31
  const int scol = (tid & 7) * 8;
  const int c16sw = (tid & 7) ^ (srow & 7);  // pre-swizzled K source chunk
  u16* lK = Ks + tid * 8;

  for (int kt = 0; kt <= qtB; ++kt) {
    const int kv0 = kt * 64;
    const bool doLow = (kt <= qtA);
    // stage K tile swizzled: linear LDS dest, inverse-swizzled global source
#pragma unroll
    for (int p = 0; p < 2; ++p) {
      const u16* gK = qkv + ((size_t)(kv0 + p * 32 + srow) * B_DIM + b) * QKV_N +
                      D_DIM + h * HD + c16sw * 8;
      async_copy16(lK + p * 256 * 8, gK);
    }
    // V: global -> regs -> scatter into MFMA B-fragment layout
    u16x8 vv[2];
#pragma unroll
    for (int p = 0; p < 2; ++p) {
      const u16* gV = qkv + ((size_t)(kv0 + p * 32 + srow) * B_DIM + b) * QKV_N +
                      2 * D_DIM + h * HD + scol;
      vv[p] = *reinterpret_cast<const u16x8*>(gV);
    }
#pragma unroll
    for (int p = 0; p < 2; ++p) {
      const int jj = srow & 7;
      const int lgrp = srow >> 3;
#pragma unroll
      for (int j = 0; j < 8; ++j) {
        const int d = scol + j;
        Vf[(((p * 4) + (d >> 4)) * 64 + lgrp * 16 + (d & 15)) * 8 + jj] = vv[p][j];
      }
    }
    __syncthreads();

    if (doLow)
      process_tile(aqA, accA, mA, lA_, kt == qtA, qAbase, kv0, l15, lg,
                   Ks, Vf, &Ps[w][0]);
    process_tile(aqB, accB, mB, lB_, kt == qtB, qBbase, kv0, l15, lg,
                 Ks, Vf, &Ps[w][0]);
    __syncthreads();
  }

  // epilogue: O /= lsum, write bf16 for both q-tiles
#pragma unroll
  for (int r = 0; r < 4; ++r) {
    const float invA = 1.0f / lA_[r];
    const float invB = 1.0f / lB_[r];
    u16* opA = aout + ((size_t)(qAbase + lg * 4 + r) * B_DIM + b) * D_DIM + h * HD;
    u16* opB = aout + ((size_t)(qBbase + lg * 4 + r) * B_DIM + b) * D_DIM + h * HD;
#pragma unroll
    for (int dj = 0; dj < 4; ++dj) {
      opA[dj * 16 + l15] = f2bf(accA[dj][r] * invA);
      opB[dj * 16 + l15] = f2bf(accB[dj][r] * invB);
    }
  }
}

// ---------------- launch ----------------
extern "C" void kernel_launch(void* const* d_in, const int* in_sizes, int n_in,
                              void* d_out, int out_size, void* d_ws, size_t ws_size,
                              hipStream_t stream) {
  (void)in_sizes; (void)n_in; (void)out_size; (void)ws_size;
  const float* x = (const float*)d_in[0];
  const float* Wqkv = (const float*)d_in[1];
  const float* Wout = (const float*)d_in[2];
  const float* bout = (const float*)d_in[3];
  float* out = (float*)d_out;

  u16* xb = (u16*)d_ws;                               // [8192][1024]
  u16* wqkvb = xb + (size_t)MROWS * D_DIM;            // [3072][1024]
  u16* woutb = wqkvb + (size_t)QKV_N * D_DIM;         // [1024][1024]
  u16* qkv = woutb + (size_t)D_DIM * D_DIM;           // [8192][3072]
  u16* aout = qkv + (size_t)MROWS * QKV_N;            // [8192][1024]

  {
    int n4 = MROWS * D_DIM / 4;
    cast_f32_bf16<<<(n4 + 255) / 256, 256, 0, stream>>>(x, xb, n4);
  }
  {
    int n4 = QKV_N * D_DIM / 4;
    cast_f32_bf16<<<(n4 + 255) / 256, 256, 0, stream>>>(Wqkv, wqkvb, n4);
  }
  {
    int n4 = D_DIM * D_DIM / 4;
    cast_f32_bf16<<<(n4 + 255) / 256, 256, 0, stream>>>(Wout, woutb, n4);
  }

  gemm_bt<0><<<dim3(QKV_N / 128, MROWS / 128), 256, 0, stream>>>(
      xb, wqkvb, qkv, nullptr, nullptr, MROWS, QKV_N, D_DIM);

  attn_kernel<<<dim3(16, B_DIM * H_NUM), 256, 0, stream>>>(qkv, aout);

  gemm_bt<1><<<dim3(D_DIM / 128, MROWS / 128), 256, 0, stream>>>(
      aout, woutb, nullptr, out, bout, MROWS, D_DIM, D_DIM);
}

// Round 4
// 213.768 us; speedup vs baseline: 2.2691x; 1.4408x over previous
//
#include <hip/hip_runtime.h>
#include <stdint.h>

// Problem constants
#define T_DIM 2048
#define B_DIM 4
#define D_DIM 1024
#define H_NUM 16
#define HD 64
#define MROWS (T_DIM * B_DIM)     // 8192 flattened (t*B+b) rows
#define QKV_N (3 * D_DIM)         // 3072
// softmax computed in log2 domain: scale = 1/sqrt(64) * log2(e)
#define ATT_C 0.18033688011112042f

typedef unsigned short u16;
typedef __bf16 bf16x8 __attribute__((ext_vector_type(8)));
typedef float f32x4 __attribute__((ext_vector_type(4)));
typedef float f32x16 __attribute__((ext_vector_type(16)));
typedef u16 u16x4 __attribute__((ext_vector_type(4)));
typedef u16 u16x8 __attribute__((ext_vector_type(8)));

__device__ __forceinline__ u16 f2bf(float f) {
  union { float f; unsigned u; } v; v.f = f;
  unsigned r = v.u + 0x7fffu + ((v.u >> 16) & 1u);
  return (u16)(r >> 16);
}

__device__ __forceinline__ void async_copy16(void* lds, const void* g) {
  __builtin_amdgcn_global_load_lds((__attribute__((address_space(1))) void*)(g),
                                   (__attribute__((address_space(3))) void*)(lds),
                                   16, 0, 0);
}

// ---------------- fp32 -> bf16 cast (memory-bound) ----------------
__global__ __launch_bounds__(256) void cast_f32_bf16(
    const float* __restrict__ src, u16* __restrict__ dst, int n4) {
  int i = blockIdx.x * 256 + threadIdx.x;
  if (i >= n4) return;
  float4 v = reinterpret_cast<const float4*>(src)[i];
  u16x4 o = {f2bf(v.x), f2bf(v.y), f2bf(v.z), f2bf(v.w)};
  reinterpret_cast<u16x4*>(dst)[i] = o;
}

// ---------------- bf16 GEMM: C[M][N] = A[M][K] * B[N][K]^T ----------------
// m97 structure (unchanged this round).
template <int OUT_F32_BIAS>
__global__ __launch_bounds__(256) void gemm_bt(
    const u16* __restrict__ A, const u16* __restrict__ Bm,
    u16* __restrict__ Cb, float* __restrict__ Cf, const float* __restrict__ bias,
    int M, int N, int K) {
  __shared__ __attribute__((aligned(16))) u16 As[128 * 64];
  __shared__ __attribute__((aligned(16))) u16 Bs[128 * 64];

  const int tid = threadIdx.x;
  const int lane = tid & 63, wid = tid >> 6;
  const int l15 = lane & 15, lg = lane >> 4;
  const int wr = wid >> 1, wc = wid & 1;
  const int m0 = blockIdx.y * 128, n0 = blockIdx.x * 128;

  f32x4 acc[4][4];
#pragma unroll
  for (int i = 0; i < 4; i++)
#pragma unroll
    for (int j = 0; j < 4; j++) acc[i][j] = (f32x4){0.f, 0.f, 0.f, 0.f};

  const int srow = tid >> 3;
  const int scol = (tid & 7) * 8;
  const u16* gA = A + (size_t)(m0 + srow) * K + scol;
  const u16* gB = Bm + (size_t)(n0 + srow) * K + scol;
  u16* lA = As + tid * 8;
  u16* lB = Bs + tid * 8;

  const int KT = K >> 6;
  for (int kt = 0; kt < KT; ++kt) {
    const int kofs = kt * 64;
#pragma unroll
    for (int p = 0; p < 4; ++p) {
      async_copy16(lA + p * 256 * 8, gA + (size_t)(p * 32) * K + kofs);
      async_copy16(lB + p * 256 * 8, gB + (size_t)(p * 32) * K + kofs);
    }
    __syncthreads();
#pragma unroll
    for (int kk = 0; kk < 2; ++kk) {
      bf16x8 af[4], bfr[4];
#pragma unroll
      for (int mt = 0; mt < 4; ++mt)
        af[mt] = *reinterpret_cast<const bf16x8*>(
            &As[(wr * 64 + mt * 16 + l15) * 64 + kk * 32 + lg * 8]);
#pragma unroll
      for (int nt = 0; nt < 4; ++nt)
        bfr[nt] = *reinterpret_cast<const bf16x8*>(
            &Bs[(wc * 64 + nt * 16 + l15) * 64 + kk * 32 + lg * 8]);
#pragma unroll
      for (int mt = 0; mt < 4; ++mt)
#pragma unroll
        for (int nt = 0; nt < 4; ++nt)
          acc[mt][nt] = __builtin_amdgcn_mfma_f32_16x16x32_bf16(
              af[mt], bfr[nt], acc[mt][nt], 0, 0, 0);
    }
    __syncthreads();
  }

#pragma unroll
  for (int mt = 0; mt < 4; ++mt) {
#pragma unroll
    for (int r = 0; r < 4; ++r) {
      const int row = m0 + wr * 64 + mt * 16 + lg * 4 + r;
#pragma unroll
      for (int nt = 0; nt < 4; ++nt) {
        const int col = n0 + wc * 64 + nt * 16 + l15;
        float v = acc[mt][nt][r];
        if (OUT_F32_BIAS) {
          Cf[(size_t)row * N + col] = v + bias[col];
        } else {
          Cb[(size_t)row * N + col] = f2bf(v);
        }
      }
    }
  }
}

// ---------------- causal flash attention, swapped-operand 32x32 ----------------
// Grid (8, B*H). Block px handles q-tiles qtA=px, qtB=15-px (128 rows each);
// 4 waves x 32 q-rows. S^T = mfma(K,Q): lane owns q = lane&31, kv split
// across hi halves -> in-lane softmax (+1 shfl_xor(32)). P->bf16 frags via
// v_cvt_pk_bf16_f32 + v_permlane32_swap_b32. O^T = mfma(V^T, P): rescale
// and epilogue in-lane. T13 defer-max (THR=8 in log2 domain).
__device__ __forceinline__ void process32(
    const bf16x8 (&qf)[4], f32x16 (&o)[2], float& m, float& l,
    int q0w, int kv0, int l31, int hi,
    const u16* __restrict__ Ks, const u16* __restrict__ Vf) {
  f32x16 s[2];
#pragma unroll
  for (int kb = 0; kb < 2; ++kb)
#pragma unroll
    for (int r = 0; r < 16; ++r) s[kb][r] = 0.f;

  // S^T[kv][q] = K . Q^T
  __builtin_amdgcn_s_setprio(1);
#pragma unroll
  for (int kb = 0; kb < 2; ++kb) {
#pragma unroll
    for (int ks = 0; ks < 4; ++ks) {
      const int row = kb * 32 + l31;
      bf16x8 kf = *reinterpret_cast<const bf16x8*>(
          &Ks[row * 64 + ((((ks << 1) | hi)) ^ (l31 & 7)) * 8]);
      s[kb] = __builtin_amdgcn_mfma_f32_32x32x16_bf16(kf, qf[ks], s[kb], 0, 0, 0);
    }
  }
  __builtin_amdgcn_s_setprio(0);

  // scale to log2 domain + causal mask + in-lane max
  const int q = q0w + l31;
  float pmax = -1e30f;
#pragma unroll
  for (int kb = 0; kb < 2; ++kb)
#pragma unroll
    for (int r = 0; r < 16; ++r) {
      const int kv = kv0 + kb * 32 + (r & 3) + ((r >> 2) << 3) + (hi << 2);
      float v = s[kb][r] * ATT_C;
      if (kv > q) v = -1e30f;
      s[kb][r] = v;
      pmax = fmaxf(pmax, v);
    }
  pmax = fmaxf(pmax, __shfl_xor(pmax, 32, 64));

  // T13 defer-max online update
  if (!__all(pmax <= m + 8.0f)) {
    const float mnew = fmaxf(m, pmax);
    const float corr = __builtin_amdgcn_exp2f(m - mnew);
    m = mnew;
    l *= corr;
#pragma unroll
    for (int db = 0; db < 2; ++db)
#pragma unroll
      for (int r = 0; r < 16; ++r) o[db][r] *= corr;
  }
  float rsum = 0.f;
#pragma unroll
  for (int kb = 0; kb < 2; ++kb)
#pragma unroll
    for (int r = 0; r < 16; ++r) {
      float p = __builtin_amdgcn_exp2f(s[kb][r] - m);
      s[kb][r] = p;
      rsum += p;
    }
  rsum += __shfl_xor(rsum, 32, 64);
  l += rsum;

  // repack P (f32, S^T layout) -> bf16 B-frags pf[ks]: lane(l31=q,hi) holds
  // P[q][ks*16 + hi*8 + j].  16 cvt_pk + 8 permlane32_swap.
  union Frag { unsigned u[4]; bf16x8 v; };
  Frag pf[4];
#pragma unroll
  for (int kb = 0; kb < 2; ++kb)
#pragma unroll
    for (int g = 0; g < 2; ++g) {
#pragma unroll
      for (int t2 = 0; t2 < 2; ++t2) {
        unsigned x, y;
        asm("v_cvt_pk_bf16_f32 %0, %1, %2"
            : "=v"(x) : "v"(s[kb][g * 8 + t2 * 2]), "v"(s[kb][g * 8 + t2 * 2 + 1]));
        asm("v_cvt_pk_bf16_f32 %0, %1, %2"
            : "=v"(y) : "v"(s[kb][g * 8 + t2 * 2 + 4]), "v"(s[kb][g * 8 + t2 * 2 + 5]));
        asm("v_permlane32_swap_b32 %0, %1" : "+v"(x), "+v"(y));
        pf[kb * 2 + g].u[t2] = x;
        pf[kb * 2 + g].u[t2 + 2] = y;
      }
    }

  // O^T[d][q] += V^T . P
  __builtin_amdgcn_s_setprio(1);
#pragma unroll
  for (int ks = 0; ks < 4; ++ks) {
#pragma unroll
    for (int db = 0; db < 2; ++db) {
      bf16x8 vf = *reinterpret_cast<const bf16x8*>(
          &Vf[(ks * 2 + db) * 512 + l31 * 16 + hi * 8]);
      o[db] = __builtin_amdgcn_mfma_f32_32x32x16_bf16(vf, pf[ks].v, o[db], 0, 0, 0);
    }
  }
  __builtin_amdgcn_s_setprio(0);
}

__global__ __launch_bounds__(256, 2) void attn_kernel(
    const u16* __restrict__ qkv, u16* __restrict__ aout) {
  __shared__ __attribute__((aligned(16))) u16 Ks[64 * 64];  // swizzled rows
  __shared__ __attribute__((aligned(16))) u16 Vf[8 * 512];  // V^T frags

  const int tid = threadIdx.x;
  const int lane = tid & 63, w = tid >> 6;
  const int l31 = lane & 31, hi = lane >> 5;
  const int px = blockIdx.x;
  const int bh = blockIdx.y;
  const int b = bh >> 4, h = bh & 15;
  const int qtA = px, qtB = 15 - px;
  const int q0A = qtA * 128 + w * 32, q0B = qtB * 128 + w * 32;

  // Q fragments: lane(l31,hi) holds Q[q0+l31][ks*16+hi*8+j]
  bf16x8 qfA[4], qfB[4];
  {
    const u16* pA = qkv + ((size_t)(q0A + l31) * B_DIM + b) * QKV_N + h * HD + hi * 8;
    const u16* pB = qkv + ((size_t)(q0B + l31) * B_DIM + b) * QKV_N + h * HD + hi * 8;
#pragma unroll
    for (int ks = 0; ks < 4; ++ks) {
      qfA[ks] = *reinterpret_cast<const bf16x8*>(pA + ks * 16);
      qfB[ks] = *reinterpret_cast<const bf16x8*>(pB + ks * 16);
    }
  }

  f32x16 oA[2], oB[2];
#pragma unroll
  for (int db = 0; db < 2; ++db)
#pragma unroll
    for (int r = 0; r < 16; ++r) { oA[db][r] = 0.f; oB[db][r] = 0.f; }
  float mA = -1e30f, lA = 0.f, mB = -1e30f, lB = 0.f;

  const int srow = tid >> 3;                 // 0..31
  const int scol = (tid & 7) * 8;
  const int csw = (tid & 7) ^ (srow & 7);    // pre-swizzled K source chunk

  const int lastKt = 2 * qtB + 1;
  for (int kt = 0; kt <= lastKt; ++kt) {
    const int kv0 = kt * 64;
    // stage K tile (swizzled: linear LDS dest, inverse-swizzled source)
#pragma unroll
    for (int p = 0; p < 2; ++p) {
      const u16* gK = qkv + ((size_t)(kv0 + p * 32 + srow) * B_DIM + b) * QKV_N +
                      D_DIM + h * HD + csw * 8;
      async_copy16(Ks + tid * 8 + p * 2048, gK);
    }
    // stage V: global -> regs -> scatter into V^T fragment layout
    u16x8 vv[2];
#pragma unroll
    for (int p = 0; p < 2; ++p) {
      const u16* gV = qkv + ((size_t)(kv0 + p * 32 + srow) * B_DIM + b) * QKV_N +
                      2 * D_DIM + h * HD + scol;
      vv[p] = *reinterpret_cast<const u16x8*>(gV);
    }
#pragma unroll
    for (int p = 0; p < 2; ++p) {
      const int kvl = p * 32 + srow;         // 0..63
      const int fb = (kvl >> 4) * 2;
      const int e16 = kvl & 15;
#pragma unroll
      for (int j = 0; j < 8; ++j) {
        const int d = scol + j;
        Vf[(fb + (d >> 5)) * 512 + (d & 31) * 16 + e16] = vv[p][j];
      }
    }
    __syncthreads();

    if (kv0 <= q0A + 31)
      process32(qfA, oA, mA, lA, q0A, kv0, l31, hi, Ks, Vf);
    if (kv0 <= q0B + 31)
      process32(qfB, oB, mB, lB, q0B, kv0, l31, hi, Ks, Vf);
    __syncthreads();
  }

  // epilogue: O^T/l -> aout ; lane(l31,hi) holds O[q=l31][d=db*32+crow(r,hi)]
#pragma unroll
  for (int t = 0; t < 2; ++t) {
    const float inv = t == 0 ? (1.0f / lA) : (1.0f / lB);
    const int q0w = t == 0 ? q0A : q0B;
    f32x16* o = t == 0 ? oA : oB;
    u16* orow = aout + ((size_t)(q0w + l31) * B_DIM + b) * D_DIM + h * HD;
#pragma unroll
    for (int db = 0; db < 2; ++db)
#pragma unroll
      for (int rq = 0; rq < 4; ++rq) {
        u16x4 o4;
#pragma unroll
        for (int e = 0; e < 4; ++e) o4[e] = f2bf(o[db][rq * 4 + e] * inv);
        *reinterpret_cast<u16x4*>(orow + db * 32 + rq * 8 + hi * 4) = o4;
      }
  }
}

// ---------------- launch ----------------
extern "C" void kernel_launch(void* const* d_in, const int* in_sizes, int n_in,
                              void* d_out, int out_size, void* d_ws, size_t ws_size,
                              hipStream_t stream) {
  (void)in_sizes; (void)n_in; (void)out_size; (void)ws_size;
  const float* x = (const float*)d_in[0];
  const float* Wqkv = (const float*)d_in[1];
  const float* Wout = (const float*)d_in[2];
  const float* bout = (const float*)d_in[3];
  float* out = (float*)d_out;

  u16* xb = (u16*)d_ws;                               // [8192][1024]
  u16* wqkvb = xb + (size_t)MROWS * D_DIM;            // [3072][1024]
  u16* woutb = wqkvb + (size_t)QKV_N * D_DIM;         // [1024][1024]
  u16* qkv = woutb + (size_t)D_DIM * D_DIM;           // [8192][3072]
  u16* aout = qkv + (size_t)MROWS * QKV_N;            // [8192][1024]

  {
    int n4 = MROWS * D_DIM / 4;
    cast_f32_bf16<<<(n4 + 255) / 256, 256, 0, stream>>>(x, xb, n4);
  }
  {
    int n4 = QKV_N * D_DIM / 4;
    cast_f32_bf16<<<(n4 + 255) / 256, 256, 0, stream>>>(Wqkv, wqkvb, n4);
  }
  {
    int n4 = D_DIM * D_DIM / 4;
    cast_f32_bf16<<<(n4 + 255) / 256, 256, 0, stream>>>(Wout, woutb, n4);
  }

  gemm_bt<0><<<dim3(QKV_N / 128, MROWS / 128), 256, 0, stream>>>(
      xb, wqkvb, qkv, nullptr, nullptr, MROWS, QKV_N, D_DIM);

  attn_kernel<<<dim3(8, B_DIM * H_NUM), 256, 0, stream>>>(qkv, aout);

  gemm_bt<1><<<dim3(D_DIM / 128, MROWS / 128), 256, 0, stream>>>(
      aout, woutb, nullptr, out, bout, MROWS, D_DIM, D_DIM);
}